// Round 11
// baseline (16203.468 us; speedup 1.0000x reference)
//
#include <hip/hip_runtime.h>
#include <hip/hip_bf16.h>
#include <math.h>

// ---------------- problem constants ----------------
#define S_LEN 2048
#define T_LEN 2048
#define HID   1024
#define GATES 4096
#define VOCAB 50257
#define SPINCAP 262144       // terminate (wrong-but-loud), never wedge the chip

typedef unsigned int u32;
typedef unsigned long long ull;
typedef u32 u32x4 __attribute__((ext_vector_type(4)));
typedef float f32x4 __attribute__((ext_vector_type(4)));

__device__ __forceinline__ float fsig_(float x)  { return 1.0f / (1.0f + __expf(-x)); }
__device__ __forceinline__ float ftanh_(float x) { float e = __expf(2.0f * x); return 1.0f - 2.0f / (e + 1.0f); }

// coherent 16B load (bypasses non-coherent per-XCD L1/L2): two packed {tag,h} slots
__device__ __forceinline__ u32x4 cload16(const ull* p) {
  u32x4 v;
  asm volatile("global_load_dwordx4 %0, %1, off sc0 sc1\n\ts_waitcnt vmcnt(0)"
               : "=v"(v) : "v"(p) : "memory");
  return v;
}

// spin until both slots' tags reach want (write-once stream, tags monotonic 0->t+1)
__device__ __forceinline__ u32x4 pollslots(const ull* p, u32 want) {
  u32x4 v = cload16(p);
  int n = 0;
  while (v.y < want || v.w < want) {
    if (++n > SPINCAP) break;
    v = cload16(p);
  }
  return v;
}

// dual poll: issue BOTH 16B loads, then one wait -> overlapped round trips.
__device__ __forceinline__ void poll2(const ull* pa, const ull* pb, u32 wa, u32 wb,
                                      u32x4& va, u32x4& vb) {
  asm volatile("global_load_dwordx4 %0, %2, off sc0 sc1\n\t"
               "global_load_dwordx4 %1, %3, off sc0 sc1\n\t"
               "s_waitcnt vmcnt(0)"
               : "=&v"(va), "=&v"(vb) : "v"(pa), "v"(pb) : "memory");
  int n = 0;
  while (va.y < wa || va.w < wa) { if (++n > SPINCAP) break; va = cload16(pa); }
  while (vb.y < wb || vb.w < wb) { if (++n > SPINCAP) break; vb = cload16(pb); }
}

// ---------------- tiny helpers ----------------
__global__ void zero_f4(float4* __restrict__ p, size_t n4) {
  size_t i = (size_t)blockIdx.x * blockDim.x + threadIdx.x;
  size_t stride = (size_t)gridDim.x * blockDim.x;
  for (; i < n4; i += stride) p[i] = make_float4(0.f, 0.f, 0.f, 0.f);
}

__global__ void build_dec_tokens(const int* __restrict__ outputs, const int* __restrict__ sos,
                                 int* __restrict__ toks, int T) {
  int t = blockIdx.x * blockDim.x + threadIdx.x;
  if (t < T) toks[t] = (t == 0) ? sos[0] : outputs[t - 1];
}

// ---------------- f32 GEMM: C[M][N] = X[M][K] @ W[N][K]^T + b1 ----------------
__global__ __launch_bounds__(256) void gemm_xwt(
    const float* __restrict__ X, const float* __restrict__ W,
    const float* __restrict__ b1,
    float* __restrict__ C, int M, int N, int K)
{
  __shared__ float Xs[16][68];
  __shared__ float Ws[16][68];
  const int tid = threadIdx.x;
  const int tx = tid & 15;
  const int ty = tid >> 4;
  const int m0 = blockIdx.y * 64;
  const int n0 = blockIdx.x * 64;
  const int lr = tid >> 2;
  const int lc = (tid & 3) * 4;
  float acc[4][4] = {{0.f}};

  for (int k0 = 0; k0 < K; k0 += 16) {
    float4 xv = *(const float4*)(X + (size_t)(m0 + lr) * K + k0 + lc);
    float4 wv = make_float4(0.f, 0.f, 0.f, 0.f);
    int wr = n0 + lr;
    if (wr < N) wv = *(const float4*)(W + (size_t)wr * K + k0 + lc);
    __syncthreads();
    Xs[lc + 0][lr] = xv.x; Xs[lc + 1][lr] = xv.y; Xs[lc + 2][lr] = xv.z; Xs[lc + 3][lr] = xv.w;
    Ws[lc + 0][lr] = wv.x; Ws[lc + 1][lr] = wv.y; Ws[lc + 2][lr] = wv.z; Ws[lc + 3][lr] = wv.w;
    __syncthreads();
#pragma unroll
    for (int kk = 0; kk < 16; ++kk) {
      float4 a = *(const float4*)&Xs[kk][ty * 4];
      float4 b = *(const float4*)&Ws[kk][tx * 4];
      float av[4] = {a.x, a.y, a.z, a.w};
      float bv[4] = {b.x, b.y, b.z, b.w};
#pragma unroll
      for (int i = 0; i < 4; ++i)
#pragma unroll
        for (int j = 0; j < 4; ++j)
          acc[i][j] = fmaf(av[i], bv[j], acc[i][j]);
    }
  }
#pragma unroll
  for (int i = 0; i < 4; ++i) {
    int m = m0 + ty * 4 + i;
#pragma unroll
    for (int j = 0; j < 4; ++j) {
      int n = n0 + tx * 4 + j;
      if (n < N) C[(size_t)m * N + n] = acc[i][j] + (b1 ? b1[n] : 0.f);
    }
  }
}

// ---------------- fused 2-layer persistent LSTM, AGPR-resident weights ----------------
// 256 WGs x 512 threads (1 WG/CU). wg<128 layer 0 (x = embedding rows, LDS
// double-buffer prefetch); wg>=128 layer 1 (x = L0 h, 1-step skew). Both fuse
// Wi@x + Wh@h. NEW decomposition: wave = 1 hidden unit; lane owns the SAME 32
// cols (8 float4 chunks of the concatenated [x,h] vector) for all 4 gate rows
// -> each x/h value is read from LDS once per wave (64KB/WG-step, 4x less) and
// reused across rows. Weights (4 rows x 32 cols = 128 f32/lane) are held in
// AGPRs via explicit v_accvgpr_write/read inline asm: values defined by
// volatile asm cannot be rematerialized as loads (the failure mode of the
// "+v"-pin in R5-R10: VGPR_Count stuck at 88, weights re-streamed from L2).
// Epilogue is in-wave: full 64-lane xor-reduce per row gives every lane all 4
// gate sums; c lives in registers; lane 0 publishes {tag,h} ASAP (no lds_g,
// no serial tail, no extra barrier). Exchange: R3-proven write-once packed 8B
// slots {tag=t+1 (hi32), f32 h (lo32)}; L1 polls both streams with dual-issue
// overlapped loads.
__global__ __launch_bounds__(512, 1) void lstm2(
    const float* __restrict__ emb,  const int* __restrict__ toks,
    const float* __restrict__ Wi0,  const float* __restrict__ Wh0,
    const float* __restrict__ bi0,  const float* __restrict__ bh0,
    const float* __restrict__ Wi1,  const float* __restrict__ Wh1,
    const float* __restrict__ bi1,  const float* __restrict__ bh1,
    const float* __restrict__ h00,  const float* __restrict__ c00,
    const float* __restrict__ h01,  const float* __restrict__ c01,
    ull* __restrict__ s0, ull* __restrict__ s1,   // [T][1024] packed slots
    float* __restrict__ hf0, float* __restrict__ cf0,
    float* __restrict__ hf1, float* __restrict__ cf1,
    float* __restrict__ dec_out, int T)
{
  const int tid   = threadIdx.x;
  const int wg    = blockIdx.x;
  const bool isL0 = (wg < 128);
  const int wgl   = isL0 ? wg : wg - 128;
  const int wlane = tid & 63;
  const int unit  = tid >> 6;           // wave index == unit 0..7

  __shared__ float lds_x[2][HID];
  __shared__ float lds_h[HID];

  const float* Wi = isL0 ? Wi0 : Wi1;
  const float* Wh = isL0 ? Wh0 : Wh1;
  const float* bi = isL0 ? bi0 : bi1;
  const float* bh = isL0 ? bh0 : bh1;

  // ---- weights -> AGPRs; biases -> VGPRs ----
  // lane wlane, gate row r: cols {4*(64*(k&3)+wlane)+e}, k<4 from Wi, k>=4 from Wh
  float bias[4];
  float Awt[128];                        // [r*32 + k*4 + e], lives in AGPR class
#pragma unroll
  for (int r = 0; r < 4; ++r) {
    const int growr = r * HID + wgl * 8 + unit;
    bias[r] = bi[growr] + bh[growr];
    const float* wiR = Wi + (size_t)growr * HID;
    const float* whR = Wh + (size_t)growr * HID;
#pragma unroll
    for (int k = 0; k < 8; ++k) {
      const float* src = (k < 4) ? wiR : whR;
      f32x4 w = *(const f32x4*)(src + 4 * (64 * (k & 3) + wlane));
      asm volatile("v_accvgpr_write_b32 %0, %1" : "=a"(Awt[r * 32 + k * 4 + 0]) : "v"(w.x));
      asm volatile("v_accvgpr_write_b32 %0, %1" : "=a"(Awt[r * 32 + k * 4 + 1]) : "v"(w.y));
      asm volatile("v_accvgpr_write_b32 %0, %1" : "=a"(Awt[r * 32 + k * 4 + 2]) : "v"(w.z));
      asm volatile("v_accvgpr_write_b32 %0, %1" : "=a"(Awt[r * 32 + k * 4 + 3]) : "v"(w.w));
    }
  }

  float creg = (isL0 ? c00 : c01)[wgl * 8 + unit];   // unit's c, replicated per lane
  {
    const float* hini = isL0 ? h00 : h01;
    if (tid < 256) ((float4*)lds_h)[tid] = ((const float4*)hini)[tid];
    if (isL0 && tid < 256) {             // stage x_0
      int tok = toks[0];
      ((float4*)lds_x[0])[tid] = ((const float4*)(emb + (size_t)tok * HID))[tid];
    }
  }
  __syncthreads();

  ull* s_mine = isL0 ? s0 : s1;

  for (int t = 0; t < T; ++t) {
    const int cur = t & 1;

    // ---- stage step inputs ----
    if (isL0) {
      if (t > 0) {
        u32x4 v = pollslots(s0 + (size_t)(t - 1) * HID + 2 * tid, (u32)t);
        lds_h[2 * tid]     = __uint_as_float(v.x);
        lds_h[2 * tid + 1] = __uint_as_float(v.z);
      }
    } else {
      if (t == 0) {
        u32x4 v = pollslots(s0 + 2 * tid, 1u);
        lds_x[0][2 * tid]     = __uint_as_float(v.x);
        lds_x[0][2 * tid + 1] = __uint_as_float(v.z);
      } else {
        u32x4 vx, vh;
        poll2(s0 + (size_t)t * HID + 2 * tid,
              s1 + (size_t)(t - 1) * HID + 2 * tid,
              (u32)(t + 1), (u32)t, vx, vh);
        lds_x[0][2 * tid]     = __uint_as_float(vx.x);
        lds_x[0][2 * tid + 1] = __uint_as_float(vx.z);
        lds_h[2 * tid]       = __uint_as_float(vh.x);
        lds_h[2 * tid + 1]   = __uint_as_float(vh.z);
      }
    }
    __syncthreads();

    // L0: prefetch x_{t+1} after the poll barrier (retires under compute)
    if (isL0 && tid < 256 && t + 1 < T) {
      int tok = toks[t + 1];
      ((float4*)lds_x[cur ^ 1])[tid] = ((const float4*)(emb + (size_t)tok * HID))[tid];
    }

    // ---- gather 8 chunks (4 x, 4 h), conflict-free consecutive float4 ----
    const float* xbuf = isL0 ? lds_x[cur] : lds_x[0];
    float4 xh[8];
#pragma unroll
    for (int k = 0; k < 4; ++k) xh[k]     = ((const float4*)xbuf)[64 * k + wlane];
#pragma unroll
    for (int k = 0; k < 4; ++k) xh[4 + k] = ((const float4*)lds_h)[64 * k + wlane];

    // ---- 4 gate rows x 32 cols: 128 FMAs from AGPR weights ----
    float sr[4];
#pragma unroll
    for (int r = 0; r < 4; ++r) {
      float acc = 0.f;
#pragma unroll
      for (int k = 0; k < 8; ++k) {
        float w0, w1, w2, w3;
        asm volatile("v_accvgpr_read_b32 %0, %1" : "=v"(w0) : "a"(Awt[r * 32 + k * 4 + 0]));
        asm volatile("v_accvgpr_read_b32 %0, %1" : "=v"(w1) : "a"(Awt[r * 32 + k * 4 + 1]));
        asm volatile("v_accvgpr_read_b32 %0, %1" : "=v"(w2) : "a"(Awt[r * 32 + k * 4 + 2]));
        asm volatile("v_accvgpr_read_b32 %0, %1" : "=v"(w3) : "a"(Awt[r * 32 + k * 4 + 3]));
        acc = fmaf(w0, xh[k].x, acc);
        acc = fmaf(w1, xh[k].y, acc);
        acc = fmaf(w2, xh[k].z, acc);
        acc = fmaf(w3, xh[k].w, acc);
      }
      sr[r] = acc;
    }

    // ---- full-wave reduce per row; every lane gets all 4 gate sums ----
#pragma unroll
    for (int r = 0; r < 4; ++r) {
      float v = sr[r];
      v += __shfl_xor(v, 1);
      v += __shfl_xor(v, 2);
      v += __shfl_xor(v, 4);
      v += __shfl_xor(v, 8);
      v += __shfl_xor(v, 16);
      v += __shfl_xor(v, 32);
      sr[r] = v + bias[r];
    }

    // ---- in-wave gate epilogue (gates r: 0=i 1=f 2=g 3=o) + publish ----
    creg = fsig_(sr[1]) * creg + fsig_(sr[0]) * ftanh_(sr[2]);
    const float h = fsig_(sr[3]) * ftanh_(creg);
    if (wlane == 0) {
      const int col = wgl * 8 + unit;
      const ull pk = ((ull)(u32)(t + 1) << 32) | (ull)__float_as_uint(h);
      __hip_atomic_store(&s_mine[(size_t)t * HID + col], pk,
                         __ATOMIC_RELAXED, __HIP_MEMORY_SCOPE_AGENT);
      if (!isL0 && dec_out) dec_out[(size_t)t * HID + col] = h;
      if (t == T - 1) {
        if (isL0) { if (hf0) hf0[col] = h; if (cf0) cf0[col] = creg; }
        else      { if (hf1) hf1[col] = h; if (cf1) cf1[col] = creg; }
      }
    }
    __syncthreads();   // LDS reuse: staging at t+1 must not overwrite live reads
  }
}

// ---------------- launch ----------------
extern "C" void kernel_launch(void* const* d_in, const int* in_sizes, int n_in,
                              void* d_out, int out_size, void* d_ws, size_t ws_size,
                              hipStream_t stream) {
  const int*   inputs  = (const int*)d_in[0];
  const int*   outputs = (const int*)d_in[1];
  const int*   sos     = (const int*)d_in[2];
  const float* enc_emb = (const float*)d_in[3];
  const float* dec_emb = (const float*)d_in[4];
  const float* enc_Wih = (const float*)d_in[5];
  const float* enc_Whh = (const float*)d_in[6];
  const float* enc_bih = (const float*)d_in[7];
  const float* enc_bhh = (const float*)d_in[8];
  const float* dec_Wih = (const float*)d_in[9];
  const float* dec_Whh = (const float*)d_in[10];
  const float* dec_bih = (const float*)d_in[11];
  const float* dec_bhh = (const float*)d_in[12];
  const float* lin_W   = (const float*)d_in[13];
  const float* lin_b   = (const float*)d_in[14];

  float* out = (float*)d_out;
  // d_out scratch: 4 packed streams (16 MB each), all dead before logits GEMM.
  ull* s0e = (ull*)d_out;
  ull* s1e = s0e + 2097152;
  ull* s0d = s1e + 2097152;
  ull* s1d = s0d + 2097152;

  char* ws = (char*)d_ws;
  float* zerosv = (float*)(ws + 0);
  float* hf0    = (float*)(ws + 4096);
  float* cf0    = (float*)(ws + 8192);
  float* hf1    = (float*)(ws + 12288);
  float* cf1    = (float*)(ws + 16384);
  int*   dtoks  = (int*)(ws + 20480);
  float* B2     = (float*)(ws + ((size_t)1 << 20));   // 8 MB: dec_out (logits X)

  const size_t WOFF = (size_t)GATES * HID;

  // zero stream tags (64 MB in d_out) + zeros vector; every call (graph replay)
  zero_f4<<<2048, 256, 0, stream>>>((float4*)d_out, 4194304);
  zero_f4<<<1, 256, 0, stream>>>((float4*)zerosv, 256);
  build_dec_tokens<<<8, 256, 0, stream>>>(outputs, sos, dtoks, T_LEN);

  // encoder: both layers, fused Wi@x, layer-pipelined
  lstm2<<<256, 512, 0, stream>>>(
      enc_emb, inputs,
      enc_Wih, enc_Whh, enc_bih, enc_bhh,
      enc_Wih + WOFF, enc_Whh + WOFF, enc_bih + GATES, enc_bhh + GATES,
      zerosv, zerosv, zerosv, zerosv,
      s0e, s1e, hf0, cf0, hf1, cf1, nullptr, S_LEN);

  // decoder: init from encoder finals; layer-1 h also written plain to B2
  lstm2<<<256, 512, 0, stream>>>(
      dec_emb, dtoks,
      dec_Wih, dec_Whh, dec_bih, dec_bhh,
      dec_Wih + WOFF, dec_Whh + WOFF, dec_bih + GATES, dec_bhh + GATES,
      hf0, cf0, hf1, cf1,
      s0d, s1d, nullptr, nullptr, nullptr, nullptr, B2, T_LEN);

  // logits
  dim3 gemmV_grid((VOCAB + 63) / 64, T_LEN / 64);
  gemm_xwt<<<gemmV_grid, 256, 0, stream>>>(B2, lin_W, lin_b, out, T_LEN, VOCAB, HID);
}

// Round 12
// 12874.789 us; speedup vs baseline: 1.2585x; 1.2585x over previous
//
#include <hip/hip_runtime.h>
#include <hip/hip_bf16.h>
#include <math.h>

// ---------------- problem constants ----------------
#define S_LEN 2048
#define T_LEN 2048
#define HID   1024
#define GATES 4096
#define VOCAB 50257

typedef unsigned int u32;
typedef unsigned short u16;
typedef unsigned long long ull;
typedef u32 u32x4 __attribute__((ext_vector_type(4)));
typedef float f32x4 __attribute__((ext_vector_type(4)));
typedef short s16x8 __attribute__((ext_vector_type(8)));   // bf16x8 MFMA fragment

__device__ __forceinline__ float fsig_(float x)  { return 1.0f / (1.0f + __expf(-x)); }
__device__ __forceinline__ float ftanh_(float x) { float e = __expf(2.0f * x); return 1.0f - 2.0f / (e + 1.0f); }

__device__ __forceinline__ u32 bf16rne(float x) {
  u32 u = __float_as_uint(x);
  return (u + 0x7FFFu + ((u >> 16) & 1u)) >> 16;
}
__device__ __forceinline__ float bf16tof(u32 b) { return __uint_as_float(b << 16); }

// ---- software-pipelined poll of two packed 8B slots {tag(hi32), h(lo32)} ----
// Depth-2: 4 dwordx2 loads in flight; s_waitcnt vmcnt(2) retires the oldest
// pair each half-RT -> detection granularity RT/2 instead of a full RT.
// Tag+data are checked ATOMICALLY via v_cmp_lt_u64 on the loaded pair
// ({tag,h} < {want,0} iff tag < want). Wave-uniform exit (s_cbranch_vccz =
// all 64 lanes ready) -- which the subsequent barrier needs anyway.
// Entry vmcnt(0) drains unrelated in-flight vmem so the counting is exact.
__device__ __forceinline__ void pollpipe2(const ull* p0, const ull* p1, u32 want,
                                          ull& ra, ull& rb) {
  ull r0a, r0b, r1a, r1b, stmp;
  u32 par;
  const ull wantv = ((ull)want) << 32;
  asm volatile(
    "s_waitcnt vmcnt(0)\n\t"
    "global_load_dwordx2 %[r0a], %[p0], off sc0 sc1\n\t"
    "global_load_dwordx2 %[r0b], %[p1], off sc0 sc1\n\t"
    "1:\n\t"
    "global_load_dwordx2 %[r1a], %[p0], off sc0 sc1\n\t"
    "global_load_dwordx2 %[r1b], %[p1], off sc0 sc1\n\t"
    "s_waitcnt vmcnt(2)\n\t"
    "v_cmp_lt_u64 vcc, %[r0a], %[wv]\n\t"
    "s_mov_b64 %[st], vcc\n\t"
    "v_cmp_lt_u64 vcc, %[r0b], %[wv]\n\t"
    "s_or_b64 vcc, vcc, %[st]\n\t"
    "s_cbranch_vccz 2f\n\t"
    "global_load_dwordx2 %[r0a], %[p0], off sc0 sc1\n\t"
    "global_load_dwordx2 %[r0b], %[p1], off sc0 sc1\n\t"
    "s_waitcnt vmcnt(2)\n\t"
    "v_cmp_lt_u64 vcc, %[r1a], %[wv]\n\t"
    "s_mov_b64 %[st], vcc\n\t"
    "v_cmp_lt_u64 vcc, %[r1b], %[wv]\n\t"
    "s_or_b64 vcc, vcc, %[st]\n\t"
    "s_cbranch_vccz 3f\n\t"
    "s_branch 1b\n\t"
    "2:\n\t"
    "s_mov_b32 %[par], 0\n\t"
    "s_branch 4f\n\t"
    "3:\n\t"
    "s_mov_b32 %[par], 1\n\t"
    "4:\n\t"
    "s_waitcnt vmcnt(0)"
    : [r0a]"=&v"(r0a), [r0b]"=&v"(r0b), [r1a]"=&v"(r1a), [r1b]"=&v"(r1b),
      [st]"=&s"(stmp), [par]"=&s"(par)
    : [p0]"v"(p0), [p1]"v"(p1), [wv]"v"(wantv)
    : "vcc", "memory");
  ra = par ? r1a : r0a;
  rb = par ? r1b : r0b;
}

// ---------------- tiny helpers ----------------
__global__ void zero_f4(float4* __restrict__ p, size_t n4) {
  size_t i = (size_t)blockIdx.x * blockDim.x + threadIdx.x;
  size_t stride = (size_t)gridDim.x * blockDim.x;
  for (; i < n4; i += stride) p[i] = make_float4(0.f, 0.f, 0.f, 0.f);
}

__global__ void build_dec_tokens(const int* __restrict__ outputs, const int* __restrict__ sos,
                                 int* __restrict__ toks, int T) {
  int t = blockIdx.x * blockDim.x + threadIdx.x;
  if (t < T) toks[t] = (t == 0) ? sos[0] : outputs[t - 1];
}

// split f32 -> bf16 hi + bf16 lo (residual), RNE
__global__ void xsplit(const float* __restrict__ x, u16* __restrict__ hi,
                       u16* __restrict__ lo, int n) {
  int i = blockIdx.x * 256 + threadIdx.x;
  if (i < n) {
    float v = x[i];
    u32 h = bf16rne(v);
    hi[i] = (u16)h;
    lo[i] = (u16)bf16rne(v - bf16tof(h));
  }
}

// ---------------- split-bf16 MFMA logits GEMM ----------------
// C[M][N] = X[M][K] @ W[N][K]^T + b.  X pre-split into Xhi/Xlo bf16; W split
// on the fly while staging into LDS. 3 accumulation terms (hi*hi + lo*hi +
// hi*lo); dropped lo*lo ~ 2^-18 relative. Block: 256 thr (4 waves), tile
// BM=128 x BN=64, BK=32; wave handles 32 rows (2 m-tiles) x 64 cols (4
// n-tiles) -> 24 mfma_f32_16x16x32_bf16 per k-step.
// Fragment layouts: A lane l -> row (l&15), k = (l>>4)*8..+8 contiguous;
// B lane l -> col (l&15) (= W row), same k pattern (k-permutation cancels
// between A and B). C/D: col = lane&15, row = (lane>>4)*4 + reg  [m89].
__global__ __launch_bounds__(256) void gemm_logits(
    const u16* __restrict__ Xhi, const u16* __restrict__ Xlo,
    const float* __restrict__ W, const float* __restrict__ b,
    float* __restrict__ C, int M, int N, int K)
{
  __shared__ u16 Bhi[64][40];
  __shared__ u16 Blo[64][40];
  const int tid = threadIdx.x;
  const int wv  = tid >> 6;
  const int l   = tid & 63;
  const int l15 = l & 15;
  const int kro = (l >> 4) * 8;
  const int m0  = blockIdx.y * 128;
  const int n0  = blockIdx.x * 64;
  const int srow = tid >> 2;          // staging: row 0..63
  const int skp  = (tid & 3) * 8;     // staging: k offset

  f32x4 acc[2][4] = {};

  for (int k0 = 0; k0 < K; k0 += 32) {
    // load W rows (guarded), split to bf16 hi/lo in regs
    float w[8] = {0.f};
    {
      int wr = n0 + srow;
      if (wr < N) {
        const float4 a = *(const float4*)(W + (size_t)wr * K + k0 + skp);
        const float4 c = *(const float4*)(W + (size_t)wr * K + k0 + skp + 4);
        w[0] = a.x; w[1] = a.y; w[2] = a.z; w[3] = a.w;
        w[4] = c.x; w[5] = c.y; w[6] = c.z; w[7] = c.w;
      }
    }
    __syncthreads();                  // previous iteration's readers done
#pragma unroll
    for (int e = 0; e < 8; ++e) {
      u32 h = bf16rne(w[e]);
      Bhi[srow][skp + e] = (u16)h;
      Blo[srow][skp + e] = (u16)bf16rne(w[e] - bf16tof(h));
    }
    __syncthreads();

    // A fragments (global, L2/L3-hot) and B fragments (LDS)
    const size_t xoff0 = (size_t)(m0 + wv * 32 + l15) * K + k0 + kro;
    const size_t xoff1 = xoff0 + (size_t)16 * K;
    s16x8 ah0 = *(const s16x8*)(Xhi + xoff0);
    s16x8 al0 = *(const s16x8*)(Xlo + xoff0);
    s16x8 ah1 = *(const s16x8*)(Xhi + xoff1);
    s16x8 al1 = *(const s16x8*)(Xlo + xoff1);
#pragma unroll
    for (int tn = 0; tn < 4; ++tn) {
      s16x8 bh = *(const s16x8*)&Bhi[tn * 16 + l15][kro];
      s16x8 bl = *(const s16x8*)&Blo[tn * 16 + l15][kro];
      acc[0][tn] = __builtin_amdgcn_mfma_f32_16x16x32_bf16(ah0, bh, acc[0][tn], 0, 0, 0);
      acc[0][tn] = __builtin_amdgcn_mfma_f32_16x16x32_bf16(al0, bh, acc[0][tn], 0, 0, 0);
      acc[0][tn] = __builtin_amdgcn_mfma_f32_16x16x32_bf16(ah0, bl, acc[0][tn], 0, 0, 0);
      acc[1][tn] = __builtin_amdgcn_mfma_f32_16x16x32_bf16(ah1, bh, acc[1][tn], 0, 0, 0);
      acc[1][tn] = __builtin_amdgcn_mfma_f32_16x16x32_bf16(al1, bh, acc[1][tn], 0, 0, 0);
      acc[1][tn] = __builtin_amdgcn_mfma_f32_16x16x32_bf16(ah1, bl, acc[1][tn], 0, 0, 0);
    }
  }

  // epilogue: C[m0+wv*32+tm*16+(l>>4)*4+r][n0+tn*16+l15] + bias
#pragma unroll
  for (int tm = 0; tm < 2; ++tm)
#pragma unroll
    for (int tn = 0; tn < 4; ++tn) {
      int n = n0 + tn * 16 + l15;
      if (n < N) {
        float bias = b[n];
#pragma unroll
        for (int r = 0; r < 4; ++r) {
          int m = m0 + wv * 32 + tm * 16 + (l >> 4) * 4 + r;
          C[(size_t)m * N + n] = acc[tm][tn][r] + bias;
        }
      }
    }
}

// ---------------- fused 2-layer persistent LSTM (R10 base + pipelined polls) ----
// 256 WGs x 512 threads (1 WG/CU). wg<128 layer 0 (x = embedding rows, LDS
// double-buffer prefetch); wg>=128 layer 1 (x = L0 h, 1-step skew). Fused
// Wi@x + Wh@h: 8 units/WG, 32 gate rows, 16 lanes/row. Exchange: write-once
// packed 8B slots {tag=t+1 (hi32), f32 h (lo32)}; consumers use the depth-2
// pipelined poll (pollpipe2) -- R11 proved compute residency doesn't set the
// period; the poll-RT quantization does.
__global__ __launch_bounds__(512, 1) void lstm2(
    const float* __restrict__ emb,  const int* __restrict__ toks,
    const float* __restrict__ Wi0,  const float* __restrict__ Wh0,
    const float* __restrict__ bi0,  const float* __restrict__ bh0,
    const float* __restrict__ Wi1,  const float* __restrict__ Wh1,
    const float* __restrict__ bi1,  const float* __restrict__ bh1,
    const float* __restrict__ h00,  const float* __restrict__ c00,
    const float* __restrict__ h01,  const float* __restrict__ c01,
    ull* __restrict__ s0, ull* __restrict__ s1,   // [T][1024] packed slots
    float* __restrict__ hf0, float* __restrict__ cf0,
    float* __restrict__ hf1, float* __restrict__ cf1,
    float* __restrict__ dec_out, int T)
{
  const int tid = threadIdx.x;
  const int wg  = blockIdx.x;
  const bool isL0 = (wg < 128);
  const int wgl = isL0 ? wg : wg - 128;

  const int lane16 = tid & 15;
  const int rloc = tid >> 4;            // 0..31 local gate row
  const int jloc = rloc & 7;
  const int gate = rloc >> 3;           // i,f,g,o
  const int grow = gate * HID + wgl * 8 + jloc;

  __shared__ float lds_x[2][HID];
  __shared__ float lds_h[HID];
  __shared__ float lds_g[32];
  __shared__ float lds_c[8];

  const float* Wi = isL0 ? Wi0 : Wi1;
  const float* Wh = isL0 ? Wh0 : Wh1;
  const float breg = (isL0 ? (bi0[grow] + bh0[grow]) : (bi1[grow] + bh1[grow]));

  f32x4 Wir[16], Whr[16];
  {
    const f32x4* wi = (const f32x4*)(Wi + (size_t)grow * HID);
    const f32x4* wh = (const f32x4*)(Wh + (size_t)grow * HID);
#pragma unroll
    for (int i = 0; i < 16; ++i) {
      Wir[i] = wi[lane16 + i * 16];
      Whr[i] = wh[lane16 + i * 16];
    }
  }

  {
    const float* hini = isL0 ? h00 : h01;
    const float* cini = isL0 ? c00 : c01;
    if (tid < 8) lds_c[tid] = cini[wgl * 8 + tid];
    if (tid < 256) ((float4*)lds_h)[tid] = ((const float4*)hini)[tid];
    if (isL0 && tid < 256) {
      int tok = toks[0];
      ((float4*)lds_x[0])[tid] = ((const float4*)(emb + (size_t)tok * HID))[tid];
    }
  }
  __syncthreads();

  ull* s_mine = isL0 ? s0 : s1;

  for (int t = 0; t < T; ++t) {
    const int cur = t & 1;

    // ---- stage step inputs via pipelined polls ----
    if (isL0) {
      if (t > 0) {
        ull va, vb;
        pollpipe2(s0 + (size_t)(t - 1) * HID + 2 * tid,
                  s0 + (size_t)(t - 1) * HID + 2 * tid + 1, (u32)t, va, vb);
        lds_h[2 * tid]     = __uint_as_float((u32)va);
        lds_h[2 * tid + 1] = __uint_as_float((u32)vb);
      }
    } else {
      {
        ull va, vb;
        pollpipe2(s0 + (size_t)t * HID + 2 * tid,
                  s0 + (size_t)t * HID + 2 * tid + 1, (u32)(t + 1), va, vb);
        lds_x[0][2 * tid]     = __uint_as_float((u32)va);
        lds_x[0][2 * tid + 1] = __uint_as_float((u32)vb);
      }
      if (t > 0) {
        ull va, vb;
        pollpipe2(s1 + (size_t)(t - 1) * HID + 2 * tid,
                  s1 + (size_t)(t - 1) * HID + 2 * tid + 1, (u32)t, va, vb);
        lds_h[2 * tid]     = __uint_as_float((u32)va);
        lds_h[2 * tid + 1] = __uint_as_float((u32)vb);
      }
    }
    __syncthreads();

    // L0: prefetch x_{t+1} after the poll barrier (retires under compute)
    if (isL0 && tid < 256 && t + 1 < T) {
      int tok = toks[t + 1];
      ((float4*)lds_x[cur ^ 1])[tid] = ((const float4*)(emb + (size_t)tok * HID))[tid];
    }

    // ---- fused gate dot: Wi@x + Wh@h ----
    const float* xbuf = isL0 ? lds_x[cur] : lds_x[0];
    float p0 = 0.f, p1 = 0.f, p2 = 0.f, p3 = 0.f;
#pragma unroll
    for (int i = 0; i < 16; ++i) {
      const float4 xv = *(const float4*)&xbuf[(lane16 << 2) + (i << 6)];
      p0 = fmaf(Wir[i].x, xv.x, p0);
      p1 = fmaf(Wir[i].y, xv.y, p1);
      p2 = fmaf(Wir[i].z, xv.z, p2);
      p3 = fmaf(Wir[i].w, xv.w, p3);
    }
#pragma unroll
    for (int i = 0; i < 16; ++i) {
      const float4 hv = *(const float4*)&lds_h[(lane16 << 2) + (i << 6)];
      p0 = fmaf(Whr[i].x, hv.x, p0);
      p1 = fmaf(Whr[i].y, hv.y, p1);
      p2 = fmaf(Whr[i].z, hv.z, p2);
      p3 = fmaf(Whr[i].w, hv.w, p3);
    }
    float sum = (p0 + p1) + (p2 + p3);
    sum += __shfl_xor(sum, 1);
    sum += __shfl_xor(sum, 2);
    sum += __shfl_xor(sum, 4);
    sum += __shfl_xor(sum, 8);
    if (lane16 == 0) lds_g[rloc] = sum + breg;
    __syncthreads();

    // ---- gate epilogue + packed publish ----
    if (tid < 8) {
      const float gi = lds_g[tid];
      const float gf = lds_g[8 + tid];
      const float gg = lds_g[16 + tid];
      const float go = lds_g[24 + tid];
      const float c = fsig_(gf) * lds_c[tid] + fsig_(gi) * ftanh_(gg);
      const float h = fsig_(go) * ftanh_(c);
      lds_c[tid] = c;
      const int col = wgl * 8 + tid;
      const ull pk = ((ull)(u32)(t + 1) << 32) | (ull)__float_as_uint(h);
      __hip_atomic_store(&s_mine[(size_t)t * HID + col], pk,
                         __ATOMIC_RELAXED, __HIP_MEMORY_SCOPE_AGENT);
      if (!isL0 && dec_out) dec_out[(size_t)t * HID + col] = h;
      if (t == T - 1) {
        if (isL0) { if (hf0) hf0[col] = h; if (cf0) cf0[col] = c; }
        else      { if (hf1) hf1[col] = h; if (cf1) cf1[col] = c; }
      }
    }
    // no trailing barrier: next step's post-poll barrier orders LDS reuse
  }
}

// ---------------- launch ----------------
extern "C" void kernel_launch(void* const* d_in, const int* in_sizes, int n_in,
                              void* d_out, int out_size, void* d_ws, size_t ws_size,
                              hipStream_t stream) {
  const int*   inputs  = (const int*)d_in[0];
  const int*   outputs = (const int*)d_in[1];
  const int*   sos     = (const int*)d_in[2];
  const float* enc_emb = (const float*)d_in[3];
  const float* dec_emb = (const float*)d_in[4];
  const float* enc_Wih = (const float*)d_in[5];
  const float* enc_Whh = (const float*)d_in[6];
  const float* enc_bih = (const float*)d_in[7];
  const float* enc_bhh = (const float*)d_in[8];
  const float* dec_Wih = (const float*)d_in[9];
  const float* dec_Whh = (const float*)d_in[10];
  const float* dec_bih = (const float*)d_in[11];
  const float* dec_bhh = (const float*)d_in[12];
  const float* lin_W   = (const float*)d_in[13];
  const float* lin_b   = (const float*)d_in[14];

  float* out = (float*)d_out;
  // d_out scratch: 4 packed streams (16 MB each), all dead before logits GEMM.
  ull* s0e = (ull*)d_out;
  ull* s1e = s0e + 2097152;
  ull* s0d = s1e + 2097152;
  ull* s1d = s0d + 2097152;

  char* ws = (char*)d_ws;
  float* zerosv = (float*)(ws + 0);
  float* hf0    = (float*)(ws + 4096);
  float* cf0    = (float*)(ws + 8192);
  float* hf1    = (float*)(ws + 12288);
  float* cf1    = (float*)(ws + 16384);
  int*   dtoks  = (int*)(ws + 20480);
  float* B2     = (float*)(ws + ((size_t)1 << 20));    // 8 MB: dec_out f32
  u16*   Xhi    = (u16*)(ws + ((size_t)10 << 20));     // 4 MB
  u16*   Xlo    = (u16*)(ws + ((size_t)15 << 20));     // 4 MB

  const size_t WOFF = (size_t)GATES * HID;

  // zero stream tags (64 MB in d_out) + zeros vector; every call (graph replay)
  zero_f4<<<2048, 256, 0, stream>>>((float4*)d_out, 4194304);
  zero_f4<<<1, 256, 0, stream>>>((float4*)zerosv, 256);
  build_dec_tokens<<<8, 256, 0, stream>>>(outputs, sos, dtoks, T_LEN);

  // encoder: both layers, fused Wi@x, layer-pipelined
  lstm2<<<256, 512, 0, stream>>>(
      enc_emb, inputs,
      enc_Wih, enc_Whh, enc_bih, enc_bhh,
      enc_Wih + WOFF, enc_Whh + WOFF, enc_bih + GATES, enc_bhh + GATES,
      zerosv, zerosv, zerosv, zerosv,
      s0e, s1e, hf0, cf0, hf1, cf1, nullptr, S_LEN);

  // decoder: init from encoder finals; layer-1 h also written plain to B2
  lstm2<<<256, 512, 0, stream>>>(
      dec_emb, dtoks,
      dec_Wih, dec_Whh, dec_bih, dec_bhh,
      dec_Wih + WOFF, dec_Whh + WOFF, dec_bih + GATES, dec_bhh + GATES,
      hf0, cf0, hf1, cf1,
      s0d, s1d, nullptr, nullptr, nullptr, nullptr, B2, T_LEN);

  // logits: split X to bf16 hi/lo, then 3-term split-bf16 MFMA GEMM
  xsplit<<<(T_LEN * HID + 255) / 256, 256, 0, stream>>>(B2, Xhi, Xlo, T_LEN * HID);
  dim3 gemmV_grid((VOCAB + 63) / 64, T_LEN / 128);
  gemm_logits<<<gemmV_grid, 256, 0, stream>>>(Xhi, Xlo, lin_W, lin_b, out,
                                              T_LEN, VOCAB, HID);
}